// Round 4
// baseline (90.392 us; speedup 1.0000x reference)
//
#include <hip/hip_runtime.h>

// Problem constants (match reference)
#define N_VOX      200000
#define N_CLUST    2000
#define CLUST_SIZE 100
#define N_EDGE     32000
#define N_FEAT     16

// Output: 6.4M points x 16 feats (fp32) = 409.6 MB -> purely write-BW-bound.
// Work item ("quad") = (point, 4-feature group): 25.6M quads.
// 4 consecutive threads own one point -> each wave's f32x4 stores form a
// dense 1 KiB contiguous block (perfect coalescing).
//
// R3 changes vs R2:
//  * NO LDS, NO __syncthreads: W sub-columns (5 x f32x4) are global-loaded
//    per thread (same-address broadcast, L1/L2 hit) -- removes the
//    ~300-400 cy barrier-serialized block prologue that taxed 50K blocks.
//  * ILP 4: each thread runs 4 independent edge_index->clusts->data chains
//    (quads t, t+Q, t+2Q, t+3Q; Q%4==0 so all share fb -> one W load).
//  * Stores stay NONTEMPORAL: 409.6 MB stream must not evict the ~5 MB
//    gather working set from L2.

#define TOTAL_QUADS (N_EDGE * 2 * CLUST_SIZE * 4)   // 25,600,000
#define QUARTER     (TOTAL_QUADS / 4)               //  6,400,000
#define BLOCK       256
#define GRID        (QUARTER / BLOCK)               // 25,000

typedef float f32x4 __attribute__((ext_vector_type(4)));

__global__ __launch_bounds__(BLOCK) void edge_enc_kernel(
    const float* __restrict__ data,        // [N_VOX, 5]
    const int*   __restrict__ clusts,      // [N_CLUST, CLUST_SIZE]
    const int*   __restrict__ edge_index,  // [2, N_EDGE]
    const float* __restrict__ W,           // [5, 16]
    float*       __restrict__ out)         // [N_EDGE*200, 16]
{
    const unsigned t = blockIdx.x * BLOCK + threadIdx.x;    // 0 .. 6.4M-1

    // All 4 quads share fb since QUARTER % 4 == 0.
    const unsigned fb = t & 3u;

    // W sub-columns: 5 rows x 4 cols, vector loads, broadcast across lanes
    // with equal fb. Independent of the gather chains -> overlapped.
    const f32x4* __restrict__ Wv = reinterpret_cast<const f32x4*>(W);
    f32x4 w0 = Wv[0 * 4 + fb];
    f32x4 w1 = Wv[1 * 4 + fb];
    f32x4 w2 = Wv[2 * 4 + fb];
    f32x4 w3 = Wv[3 * 4 + fb];
    f32x4 w4 = Wv[4 * 4 + fb];

    // ---- 4 independent index chains ----
    unsigned p[4], e[4], v[4], s[4];
#pragma unroll
    for (int k = 0; k < 4; ++k) {
        const unsigned g = t + (unsigned)(k * QUARTER);
        p[k] = g >> 2;
        e[k] = p[k] / 200u;                 // magic-mul
        const unsigned j = p[k] - e[k] * 200u;
        s[k] = (j >= 100u) ? 1u : 0u;
        v[k] = j - s[k] * 100u;
    }

    int c[4];
#pragma unroll
    for (int k = 0; k < 4; ++k)
        c[k] = edge_index[s[k] * N_EDGE + e[k]];

    int vox[4];
#pragma unroll
    for (int k = 0; k < 4; ++k)
        vox[k] = clusts[c[k] * CLUST_SIZE + (int)v[k]];

    float x0[4], x1[4], x2[4], x3[4], x4[4];
#pragma unroll
    for (int k = 0; k < 4; ++k) {
        const float* dr = data + (size_t)vox[k] * 5;
        x0[k] = dr[0];
        x1[k] = dr[1];
        x2[k] = dr[2];
        x3[k] = (float)e[k];                // batch-id column := edge id
        x4[k] = dr[4];
    }

    // ---- compute + nontemporal dense stores ----
#pragma unroll
    for (int k = 0; k < 4; ++k) {
        f32x4 r;
#pragma unroll
        for (int q = 0; q < 4; ++q) {
            float a = fmaf(x0[k], w0[q], fmaf(x1[k], w1[q], fmaf(x2[k], w2[q],
                      fmaf(x3[k], w3[q], x4[k] * w4[q]))));
            r[q] = fmaxf(a, 0.0f);
        }
        __builtin_nontemporal_store(r,
            reinterpret_cast<f32x4*>(out + (size_t)p[k] * N_FEAT + fb * 4u));
    }
}

extern "C" void kernel_launch(void* const* d_in, const int* in_sizes, int n_in,
                              void* d_out, int out_size, void* d_ws, size_t ws_size,
                              hipStream_t stream) {
    const float* data       = (const float*)d_in[0];
    const int*   clusts     = (const int*)d_in[1];
    const int*   edge_index = (const int*)d_in[2];
    const float* W          = (const float*)d_in[3];
    float*       out        = (float*)d_out;

    edge_enc_kernel<<<GRID, BLOCK, 0, stream>>>(data, clusts, edge_index, W, out);
}